// Round 9
// baseline (135.958 us; speedup 1.0000x reference)
//
#include <hip/hip_runtime.h>
#include <hip/hip_bf16.h>

#define CC 728
#define PP 364          // pairs (even/odd phase length)
#define KP 384          // padded pair-K: 12 * 32
#define KT 12
#define MT 361          // m-tiles of 128 rows  (46208 = 361*128)
#define NT 8            // n-tiles of 48 pair-cols (384 >= 364)
#define NBP 48          // pair-cols per block
#define NWG (MT * NT)   // 2888

typedef __attribute__((ext_vector_type(8))) short bf16x8;
typedef __attribute__((ext_vector_type(4))) float f32x4;

// round-to-nearest-even fp32 -> bf16 bits
__device__ __forceinline__ unsigned int f2bf(float f) {
    unsigned int u = __float_as_uint(f);
    unsigned int r = u + 0x7fffu + ((u >> 16) & 1u);
    return r >> 16;
}

__device__ __forceinline__ void gload_lds16(const void* g, void* l) {
    __builtin_amdgcn_global_load_lds(
        (const __attribute__((address_space(1))) void*)g,
        (__attribute__((address_space(3))) void*)l,
        16, 0, 0);
}

// h[d] for odd d (validated closed form, rounds 1-7):
//   h[d] = s * cos(pi d/728) / (728 sin(pi d/728)),  s = +1 if (d>>1)&1 else -1
// Bt1[n][k] = h[2*((n-k-1) mod 364)+1]   (Ye = 0.5 E + Bt1 . O)
// Bt2[n][k] = h[2*((n-k)   mod 364)+1]   (Yo = 0.5 O + Bt2 . E)
// Both padded to [384][384] bf16, zero outside n<364 && k<364.
__global__ void build_bt(unsigned short* __restrict__ bt1,
                         unsigned short* __restrict__ bt2) {
    int idx = blockIdx.x * blockDim.x + threadIdx.x;
    if (idx >= 2 * KP * KP) return;
    int mat = idx / (KP * KP);
    int rem = idx % (KP * KP);
    int n = rem / KP, k = rem % KP;
    float v = 0.f;
    if (n < PP && k < PP) {
        int m = n - k - (mat == 0 ? 1 : 0);
        if (m < 0) m += PP;
        int d = 2 * m + 1;
        float t = (float)(3.14159265358979323846 * (double)d / (double)CC);
        float s = ((d >> 1) & 1) ? 1.f : -1.f;
        v = s * cosf(t) / ((float)CC * sinf(t));
    }
    (mat == 0 ? bt1 : bt2)[n * KP + k] = (unsigned short)f2bf(v);
}

// Barrier-free even/odd split GEMM.
// Block: 128 rows x 48 pair-cols; 4 waves, each 32 rows x 48 pair-cols.
// B slices (both tables) staged ONCE into 72 KB LDS (XOR-swizzled), then the
// K-loop is pure {global A loads -> reg cvt -> LDS B reads -> MFMA} with NO
// barriers and NO vmcnt drains: each wave pipelines independently.
__global__ __launch_bounds__(256, 2) void gemm_relu(
        const float* __restrict__ x,
        const unsigned short* __restrict__ bt1,
        const unsigned short* __restrict__ bt2,
        float* __restrict__ out) {
    __shared__ unsigned short ldsB[2 * NBP * KP];   // 73728 B

    const int tid  = threadIdx.x;
    const int lane = tid & 63;
    const int wid  = tid >> 6;
    const int l15  = lane & 15, lhi = lane >> 4;    // lhi in 0..3

    // XCD swizzle: NWG % 8 == 0 -> each XCD gets 361 consecutive wgids;
    // n-tile cycles fastest (8 n-tiles per m-panel, all on one XCD's L2).
    int orig = blockIdx.x;
    int wgid = (orig & 7) * (NWG / 8) + (orig >> 3);
    const int bm  = (wgid / NT) * 128;
    const int bnp = (wgid % NT) * NBP;              // pair-col base

    // ---- one-time B stage: 4608 16B chunks, XOR-swizzled via source ----
#pragma unroll
    for (int i = 0; i < 18; ++i) {
        int c     = i * 256 + tid;                  // chunk id
        int ncomb = c / 48;                         // 0..95 (48 chunks/row)
        int kb    = (c % 48) * 16;                  // byte offset in row
        int tbl   = (ncomb >= NBP) ? 1 : 0;
        int lrow  = ncomb - tbl * NBP;              // 0..47
        const unsigned short* base = tbl ? bt2 : bt1;
        size_t so = (size_t)(bnp + lrow) * (KP * 2) + (kb ^ ((lrow & 7) << 4));
        gload_lds16((const char*)base + so, (char*)ldsB + (size_t)c * 16);
    }
    __syncthreads();    // the ONLY barrier

    f32x4 acc_e[2][3], acc_o[2][3];
#pragma unroll
    for (int i = 0; i < 2; ++i)
#pragma unroll
        for (int j = 0; j < 3; ++j)
#pragma unroll
            for (int rr = 0; rr < 4; ++rr) { acc_e[i][j][rr] = 0.f; acc_o[i][j][rr] = 0.f; }

    // per-lane A row pointers (m-frag rows: l15; two m-frags per wave)
    const float* xr0 = x + (size_t)(bm + wid * 32 + l15) * CC;
    const float* xr1 = xr0 + (size_t)16 * CC;

    // B frag read: row = nf*16+l15, 16B at (kt*64+lhi*16) XOR row-swizzle
    auto ldB = [&](int tbl, int nf, int kt) -> bf16x8 {
        int lrow = nf * 16 + l15;
        int off  = tbl * (NBP * KP * 2) + lrow * (KP * 2)
                 + ((kt * 64 + lhi * 16) ^ ((lrow & 7) << 4));
        return *(const bf16x8*)((const char*)ldsB + off);
    };

    // A loads: 16 consecutive channels per m-frag (4 float4), tail-guarded
    float4 fb[2][2][4];
    auto loadA = [&](int kt, int st) {
        int cb0 = kt * 64 + lhi * 16;
        const float* p0 = xr0 + cb0;
        const float* p1 = xr1 + cb0;
#pragma unroll
        for (int j = 0; j < 4; ++j) {
            bool ok = (cb0 + 4 * j) < CC;           // only kt=11 divergent
            fb[st][0][j] = ok ? ((const float4*)p0)[j] : make_float4(0.f, 0.f, 0.f, 0.f);
            fb[st][1][j] = ok ? ((const float4*)p1)[j] : make_float4(0.f, 0.f, 0.f, 0.f);
        }
    };

    loadA(0, 0);
#pragma unroll
    for (int kt = 0; kt < KT; ++kt) {
        if (kt + 1 < KT) loadA(kt + 1, (kt + 1) & 1);

        bf16x8 b1f[3], b2f[3];
#pragma unroll
        for (int nf = 0; nf < 3; ++nf) {
            b1f[nf] = ldB(0, nf, kt);
            b2f[nf] = ldB(1, nf, kt);
        }

        // in-reg de-interleave + cvt (scalar RNE bit-twiddle, packed)
        bf16x8 aE[2], aO[2];
#pragma unroll
        for (int mi = 0; mi < 2; ++mi) {
            union { bf16x8 v; unsigned int u[4]; } ue, uo;
#pragma unroll
            for (int j = 0; j < 4; ++j) {
                float4 f = fb[kt & 1][mi][j];
                ue.u[j] = f2bf(f.x) | (f2bf(f.z) << 16);
                uo.u[j] = f2bf(f.y) | (f2bf(f.w) << 16);
            }
            aE[mi] = ue.v; aO[mi] = uo.v;
        }

#pragma unroll
        for (int mi = 0; mi < 2; ++mi)
#pragma unroll
            for (int nf = 0; nf < 3; ++nf) {
                acc_e[mi][nf] = __builtin_amdgcn_mfma_f32_16x16x32_bf16(
                    aO[mi], b1f[nf], acc_e[mi][nf], 0, 0, 0);
                acc_o[mi][nf] = __builtin_amdgcn_mfma_f32_16x16x32_bf16(
                    aE[mi], b2f[nf], acc_o[mi][nf], 0, 0, 0);
            }
    }

    // ---- epilogue: +0.5x identity (L2-hot re-read), relu, float2 store ----
#pragma unroll
    for (int mi = 0; mi < 2; ++mi) {
#pragma unroll
        for (int nf = 0; nf < 3; ++nf) {
            int colp = bnp + nf * 16 + l15;
            if (colp < PP) {
#pragma unroll
                for (int rr = 0; rr < 4; ++rr) {
                    int rowg = bm + wid * 32 + mi * 16 + lhi * 4 + rr;
                    size_t base = (size_t)rowg * CC + 2 * colp;
                    float2 xv = *(const float2*)&x[base];
                    float2 o;
                    float ye = 0.5f * xv.x + acc_e[mi][nf][rr];
                    float yo = 0.5f * xv.y + acc_o[mi][nf][rr];
                    o.x = ye > 0.f ? ye : 0.f;
                    o.y = yo > 0.f ? yo : 0.f;
                    *(float2*)&out[base] = o;
                }
            }
        }
    }
}

extern "C" void kernel_launch(void* const* d_in, const int* in_sizes, int n_in,
                              void* d_out, int out_size, void* d_ws, size_t ws_size,
                              hipStream_t stream) {
    const float* x = (const float*)d_in[0];
    float* out = (float*)d_out;

    unsigned short* bt1 = (unsigned short*)d_ws;            // 384*384 bf16
    unsigned short* bt2 = bt1 + KP * KP;                    // 384*384 bf16

    build_bt<<<(2 * KP * KP + 255) / 256, 256, 0, stream>>>(bt1, bt2);
    gemm_relu<<<NWG, 256, 0, stream>>>(x, bt1, bt2, out);
}

// Round 10
// 116.661 us; speedup vs baseline: 1.1654x; 1.1654x over previous
//
#include <hip/hip_runtime.h>
#include <hip/hip_bf16.h>

#define CC 728
#define PP 364          // pairs (even/odd phase length)
#define KP 384          // padded pair-K: 12 * 32
#define KT 12
#define M_ROWS 46208    // 32*38*38 = 361 * 128
#define NWG 2166        // 361 m-tiles * 6 n-tiles (64 pairs each)

typedef __attribute__((ext_vector_type(8))) short bf16x8;
typedef __attribute__((ext_vector_type(8))) unsigned short ushort8;
typedef __attribute__((ext_vector_type(4))) float f32x4;

// round-to-nearest-even fp32 -> bf16 bits
__device__ __forceinline__ unsigned int f2bf(float f) {
    unsigned int u = __float_as_uint(f);
    unsigned int r = u + 0x7fffu + ((u >> 16) & 1u);
    return r >> 16;
}

__device__ __forceinline__ float bf2f(unsigned short v) {
    unsigned int u = ((unsigned int)v) << 16;
    return __uint_as_float(u);
}

__device__ __forceinline__ void gload_lds16(const void* g, void* l) {
    __builtin_amdgcn_global_load_lds(
        (const __attribute__((address_space(1))) void*)g,
        (__attribute__((address_space(3))) void*)l,
        16, 0, 0);
}

// h[d] for odd d (validated closed form, rounds 1-9):
//   h[d] = s * cos(pi d/728) / (728 sin(pi d/728)),  s = +1 if (d>>1)&1 else -1
// Bt1[n][k] = h[2*((n-k-1) mod 364)+1]   (Ye = 0.5 E + Bt1 . O)
// Bt2[n][k] = h[2*((n-k)   mod 364)+1]   (Yo = 0.5 O + Bt2 . E)
// Both padded to [384][384] bf16, zero outside n<364 && k<364.
__global__ void build_bt(unsigned short* __restrict__ bt1,
                         unsigned short* __restrict__ bt2) {
    int idx = blockIdx.x * blockDim.x + threadIdx.x;
    if (idx >= 2 * KP * KP) return;
    int mat = idx / (KP * KP);
    int rem = idx % (KP * KP);
    int n = rem / KP, k = rem % KP;
    float v = 0.f;
    if (n < PP && k < PP) {
        int m = n - k - (mat == 0 ? 1 : 0);
        if (m < 0) m += PP;
        int d = 2 * m + 1;
        float t = (float)(3.14159265358979323846 * (double)d / (double)CC);
        float s = ((d >> 1) & 1) ? 1.f : -1.f;
        v = s * cosf(t) / ((float)CC * sinf(t));
    }
    (mat == 0 ? bt1 : bt2)[n * KP + k] = (unsigned short)f2bf(v);
}

// Pass 1: x fp32 [46208][728] -> e,o bf16 [46208][384] (de-interleaved, padded)
__global__ void convert_deint(const float* __restrict__ x,
                              unsigned short* __restrict__ e,
                              unsigned short* __restrict__ o) {
    int id = blockIdx.x * blockDim.x + threadIdx.x;   // r*48 + p8
    if (id >= M_ROWS * 48) return;
    int r  = id / 48, p8 = id % 48;
    int c0 = p8 * 16;
    ushort8 ve, vo;
#pragma unroll
    for (int j = 0; j < 8; ++j) { ve[j] = 0; vo[j] = 0; }
    if (c0 < CC) {
        const float4* src = (const float4*)(x + (size_t)r * CC + c0);
#pragma unroll
        for (int j = 0; j < 4; ++j) {
            float4 f = (c0 + 4 * j < CC) ? src[j] : make_float4(0.f, 0.f, 0.f, 0.f);
            ve[2 * j]     = (unsigned short)f2bf(f.x);
            vo[2 * j]     = (unsigned short)f2bf(f.y);
            ve[2 * j + 1] = (unsigned short)f2bf(f.z);
            vo[2 * j + 1] = (unsigned short)f2bf(f.w);
        }
    }
    *(ushort8*)(e + (size_t)r * KP + p8 * 8) = ve;
    *(ushort8*)(o + (size_t)r * KP + p8 * 8) = vo;
}

// Pass 2: split GEMM, all operands bf16, ALL staging via global_load_lds
// (no in-loop cvt, no reg round-trip). 128 rows x 64 pair-cols per block,
// single-buffer 24KB LDS, 2 barriers/step (R1/R5 proven schedule).
//   out[r][2n]   = relu(0.5 E[r][n] + sum_k Bt1[n][k] * O[r][k])
//   out[r][2n+1] = relu(0.5 O[r][n] + sum_k Bt2[n][k] * E[r][k])
__global__ __launch_bounds__(256) void gemm_relu(
        const unsigned short* __restrict__ e,
        const unsigned short* __restrict__ o,
        const unsigned short* __restrict__ bt1,
        const unsigned short* __restrict__ bt2,
        float* __restrict__ out) {
    __shared__ unsigned short ldsE[128 * 32];    // 8 KB
    __shared__ unsigned short ldsO[128 * 32];    // 8 KB
    __shared__ unsigned short ldsB1[64 * 32];    // 4 KB
    __shared__ unsigned short ldsB2[64 * 32];    // 4 KB

    const int tid  = threadIdx.x;
    const int lane = tid & 63;
    const int wid  = tid >> 6;
    const int wr   = wid >> 1, wc = wid & 1;     // 2x2 wave grid
    const int l15  = lane & 15, lhi = lane >> 4;

    // bijective XCD swizzle (m204); 6 consecutive wgids share an A row-panel
    const int NX = 8;
    int orig = blockIdx.x;
    int q = NWG / NX, r = NWG % NX;              // 270, 6
    int xcd = orig % NX, local = orig / NX;
    int wgid = (xcd < r ? xcd * (q + 1) : r * (q + 1) + (xcd - r) * q) + local;
    const int bm  = (wgid / 6) * 128;
    const int bnp = (wgid % 6) * 64;             // pair-col base

    f32x4 acc_e[4][2], acc_o[4][2];
#pragma unroll
    for (int i = 0; i < 4; ++i)
#pragma unroll
        for (int j = 0; j < 2; ++j)
#pragma unroll
            for (int rr = 0; rr < 4; ++rr) { acc_e[i][j][rr] = 0.f; acc_o[i][j][rr] = 0.f; }

    const int rowA = tid >> 2;     // 0..63 base row for E/O chunks (c>>2 full)
    const int cq   = tid & 3;      // 8-pair (16B) chunk id

    for (int kt = 0; kt < KT; ++kt) {
        const int k0 = kt * 32;    // pair-k base

        // ---- stage E,O [128][32] (2 DMA each) + B1,B2 [64][32] (1 DMA each)
        // linear LDS dest, rotation-swizzled global source (rule 21) ----
#pragma unroll
        for (int i = 0; i < 2; ++i) {
            int row  = i * 64 + rowA;
            int gsrc = (cq - (row >> 1)) & 3;
            size_t so = (size_t)(bm + row) * KP + k0 + gsrc * 8;
            gload_lds16(e + so, &ldsE[(i * 256 + tid) * 8]);
            gload_lds16(o + so, &ldsO[(i * 256 + tid) * 8]);
        }
        {
            int row  = rowA;                      // 0..63
            int gsrc = (cq - (row >> 1)) & 3;
            size_t so = (size_t)(bnp + row) * KP + k0 + gsrc * 8;
            gload_lds16(bt1 + so, &ldsB1[tid * 8]);
            gload_lds16(bt2 + so, &ldsB2[tid * 8]);
        }
        __syncthreads();   // drains DMA (vmcnt) before reads

        // ---- frags + MFMA ----
        bf16x8 aE[4], aO[4], b1[2], b2[2];
#pragma unroll
        for (int mi = 0; mi < 4; ++mi) {
            int row = wr * 64 + mi * 16 + l15;
            int c   = (lhi + (row >> 1)) & 3;
            aE[mi] = *(const bf16x8*)&ldsE[row * 32 + c * 8];
            aO[mi] = *(const bf16x8*)&ldsO[row * 32 + c * 8];
        }
#pragma unroll
        for (int nf = 0; nf < 2; ++nf) {
            int row = wc * 32 + nf * 16 + l15;
            int c   = (lhi + (row >> 1)) & 3;
            b1[nf] = *(const bf16x8*)&ldsB1[row * 32 + c * 8];
            b2[nf] = *(const bf16x8*)&ldsB2[row * 32 + c * 8];
        }
        __builtin_amdgcn_s_setprio(1);
#pragma unroll
        for (int mi = 0; mi < 4; ++mi)
#pragma unroll
            for (int nf = 0; nf < 2; ++nf) {
                acc_e[mi][nf] = __builtin_amdgcn_mfma_f32_16x16x32_bf16(
                    aO[mi], b1[nf], acc_e[mi][nf], 0, 0, 0);
                acc_o[mi][nf] = __builtin_amdgcn_mfma_f32_16x16x32_bf16(
                    aE[mi], b2[nf], acc_o[mi][nf], 0, 0, 0);
            }
        __builtin_amdgcn_s_setprio(0);
        __syncthreads();   // protect single-buffered LDS
    }

    // ---- epilogue: +0.5*E/O identity (bf16 re-read), relu, float2 store ----
#pragma unroll
    for (int mi = 0; mi < 4; ++mi) {
#pragma unroll
        for (int nf = 0; nf < 2; ++nf) {
            int colp = bnp + wc * 32 + nf * 16 + l15;
            if (colp < PP) {
#pragma unroll
                for (int rr = 0; rr < 4; ++rr) {
                    int rowg = bm + wr * 64 + mi * 16 + lhi * 4 + rr;
                    size_t ib = (size_t)rowg * KP + colp;
                    float fe = bf2f(e[ib]);
                    float fo = bf2f(o[ib]);
                    float ye = 0.5f * fe + acc_e[mi][nf][rr];
                    float yo = 0.5f * fo + acc_o[mi][nf][rr];
                    float2 ov;
                    ov.x = ye > 0.f ? ye : 0.f;
                    ov.y = yo > 0.f ? yo : 0.f;
                    *(float2*)&out[(size_t)rowg * CC + 2 * colp] = ov;
                }
            }
        }
    }
}

extern "C" void kernel_launch(void* const* d_in, const int* in_sizes, int n_in,
                              void* d_out, int out_size, void* d_ws, size_t ws_size,
                              hipStream_t stream) {
    const float* x = (const float*)d_in[0];
    float* out = (float*)d_out;

    unsigned short* bt1 = (unsigned short*)d_ws;            // 384*384 bf16
    unsigned short* bt2 = bt1 + KP * KP;
    unsigned short* e   = bt2 + KP * KP;                    // 46208*384 bf16
    unsigned short* o   = e + (size_t)M_ROWS * KP;

    build_bt<<<(2 * KP * KP + 255) / 256, 256, 0, stream>>>(bt1, bt2);
    convert_deint<<<(M_ROWS * 48) / 256, 256, 0, stream>>>(x, e, o);
    gemm_relu<<<NWG, 256, 0, stream>>>(e, o, bt1, bt2, out);
}

// Round 11
// 107.061 us; speedup vs baseline: 1.2699x; 1.0897x over previous
//
#include <hip/hip_runtime.h>
#include <hip/hip_bf16.h>

#define CC 728
#define PP 364          // pairs (even/odd phase length)
#define KP 384          // padded pair-K: 12 * 32
#define KT 12
#define M_ROWS 46208    // 32*38*38 = 722 * 64
#define NWG 2166        // 722 m-tiles * 3 pair-n tiles

typedef __attribute__((ext_vector_type(8))) short bf16x8;
typedef __attribute__((ext_vector_type(8))) unsigned short ushort8;
typedef __attribute__((ext_vector_type(4))) float f32x4;

// round-to-nearest-even fp32 -> bf16 bits
__device__ __forceinline__ unsigned int f2bf(float f) {
    unsigned int u = __float_as_uint(f);
    unsigned int r = u + 0x7fffu + ((u >> 16) & 1u);
    return r >> 16;
}

__device__ __forceinline__ void gload_lds16(const void* g, void* l) {
    __builtin_amdgcn_global_load_lds(
        (const __attribute__((address_space(1))) void*)g,
        (__attribute__((address_space(3))) void*)l,
        16, 0, 0);
}

// h[d] for odd d (validated closed form, rounds 1-10):
//   h[d] = s * cos(pi d/728) / (728 sin(pi d/728)),  s = +1 if (d>>1)&1 else -1
// Bt1[n][k] = h[2*((n-k-1) mod 364)+1]   (Ye = 0.5 E + Bt1 . O)
// Bt2[n][k] = h[2*((n-k)   mod 364)+1]   (Yo = 0.5 O + Bt2 . E)
// Both padded to [384][384] bf16, zero outside n<364 && k<364.
__global__ void build_bt(unsigned short* __restrict__ bt1,
                         unsigned short* __restrict__ bt2) {
    int idx = blockIdx.x * blockDim.x + threadIdx.x;
    if (idx >= 2 * KP * KP) return;
    int mat = idx / (KP * KP);
    int rem = idx % (KP * KP);
    int n = rem / KP, k = rem % KP;
    float v = 0.f;
    if (n < PP && k < PP) {
        int m = n - k - (mat == 0 ? 1 : 0);
        if (m < 0) m += PP;
        int d = 2 * m + 1;
        float t = (float)(3.14159265358979323846 * (double)d / (double)CC);
        float s = ((d >> 1) & 1) ? 1.f : -1.f;
        v = s * cosf(t) / ((float)CC * sinf(t));
    }
    (mat == 0 ? bt1 : bt2)[n * KP + k] = (unsigned short)f2bf(v);
}

// Fused even/odd split GEMM (single pass over x).
// 64 rows x 128 pair-cols per block. Raw s_barrier + counted vmcnt pipeline:
// A(t+1) fp32 reg-prefetch and B(t+1) DMA stay in flight across barriers;
// only L2-hot B(t) is drained before compute.
//   out[r][2n]   = relu(0.5 x[r][2n]   + sum_k Bt1[n][k] * x[r][2k+1])
//   out[r][2n+1] = relu(0.5 x[r][2n+1] + sum_k Bt2[n][k] * x[r][2k])
__global__ __launch_bounds__(256) void gemm_relu(
        const float* __restrict__ x,
        const unsigned short* __restrict__ bt1,
        const unsigned short* __restrict__ bt2,
        float* __restrict__ out) {
    __shared__ unsigned short ldsE[64 * 32];        // 4 KB (single buf)
    __shared__ unsigned short ldsO[64 * 32];        // 4 KB
    __shared__ unsigned short ldsB1[2][128 * 32];   // 2 x 8 KB (double buf)
    __shared__ unsigned short ldsB2[2][128 * 32];   // 2 x 8 KB  => 40 KB

    const int tid  = threadIdx.x;
    const int lane = tid & 63;
    const int wid  = tid >> 6;
    const int wr   = wid >> 1, wc = wid & 1;     // 2x2 wave grid
    const int l15  = lane & 15, lhi = lane >> 4;

    // bijective XCD swizzle (m204); 3 consecutive wgids share an A row-panel
    const int NX = 8;
    int orig = blockIdx.x;
    int q = NWG / NX, r = NWG % NX;              // 270, 6
    int xcd = orig % NX, local = orig / NX;
    int wgid = (xcd < r ? xcd * (q + 1) : r * (q + 1) + (xcd - r) * q) + local;
    const int bm  = (wgid / 3) * 64;
    const int bnp = (wgid % 3) * 128;            // pair-col base

    f32x4 acc_e[2][4], acc_o[2][4];
#pragma unroll
    for (int i = 0; i < 2; ++i)
#pragma unroll
        for (int j = 0; j < 4; ++j)
#pragma unroll
            for (int rr = 0; rr < 4; ++rr) { acc_e[i][j][rr] = 0.f; acc_o[i][j][rr] = 0.f; }

    const int brow = tid >> 2;     // B-staging row within 64-row issue
    const int bc   = tid & 3;      // B 8-elem chunk id
    const int arow = tid >> 2;     // A-staging row (0..63)
    const int acx  = tid & 3;      // A 16-channel chunk id

    // ---- staging helpers (indexing identical to validated R5/R10) ----
    auto stageB = [&](int buf, int kt) {        // 4 DMA / thread
        int k0 = kt * 32;
#pragma unroll
        for (int i = 0; i < 2; ++i) {
            int rr   = i * 64 + brow;
            int gsrc = (bc - (rr >> 1)) & 3;
            size_t so = (size_t)(bnp + rr) * KP + k0 + gsrc * 8;
            gload_lds16(bt1 + so, &ldsB1[buf][(i * 256 + tid) * 8]);
            gload_lds16(bt2 + so, &ldsB2[buf][(i * 256 + tid) * 8]);
        }
    };
    auto loadA = [&](int kt, float4 (&va)[4]) { // 4 reg-loads / thread
        int cb0 = kt * 64 + acx * 16;
        const float* src = x + (size_t)(bm + arow) * CC + cb0;
#pragma unroll
        for (int i = 0; i < 4; ++i)
            va[i] = (cb0 + 4 * i < CC) ? ((const float4*)src)[i]
                                       : make_float4(0.f, 0.f, 0.f, 0.f);
    };
    auto writeA = [&](const float4 (&va)[4]) {
        ushort8 oe, oo;
#pragma unroll
        for (int p = 0; p < 4; ++p) {
            float4 f = va[p];
            oe[2 * p]     = (unsigned short)f2bf(f.x);
            oo[2 * p]     = (unsigned short)f2bf(f.y);
            oe[2 * p + 1] = (unsigned short)f2bf(f.z);
            oo[2 * p + 1] = (unsigned short)f2bf(f.w);
        }
        int sc = (acx + (arow >> 1)) & 3;
        *(ushort8*)&ldsE[arow * 32 + sc * 8] = oe;
        *(ushort8*)&ldsO[arow * 32 + sc * 8] = oo;
    };
    auto compute = [&](int buf) {
        bf16x8 aE[2], aO[2], b1[4], b2[4];
#pragma unroll
        for (int mi = 0; mi < 2; ++mi) {
            int row = wr * 32 + mi * 16 + l15;
            int c   = (lhi + (row >> 1)) & 3;
            aE[mi] = *(const bf16x8*)&ldsE[row * 32 + c * 8];
            aO[mi] = *(const bf16x8*)&ldsO[row * 32 + c * 8];
        }
#pragma unroll
        for (int nj = 0; nj < 4; ++nj) {
            int row = wc * 64 + nj * 16 + l15;
            int c   = (lhi + (row >> 1)) & 3;
            b1[nj] = *(const bf16x8*)&ldsB1[buf][row * 32 + c * 8];
            b2[nj] = *(const bf16x8*)&ldsB2[buf][row * 32 + c * 8];
        }
        __builtin_amdgcn_s_setprio(1);
#pragma unroll
        for (int mi = 0; mi < 2; ++mi)
#pragma unroll
            for (int nj = 0; nj < 4; ++nj) {
                acc_e[mi][nj] = __builtin_amdgcn_mfma_f32_16x16x32_bf16(
                    aO[mi], b1[nj], acc_e[mi][nj], 0, 0, 0);
                acc_o[mi][nj] = __builtin_amdgcn_mfma_f32_16x16x32_bf16(
                    aE[mi], b2[nj], acc_o[mi][nj], 0, 0, 0);
            }
        __builtin_amdgcn_s_setprio(0);
    };

    // one pipelined step; static buffer/register assignment (rule 20)
    auto step = [&](int t, const float4 (&vaCur)[4], float4 (&vaNxt)[4],
                    int curbuf, int nxtbuf) {
        // entry outstanding: va(t)=4 (oldest), B(t)=4
        asm volatile("s_waitcnt vmcnt(4)" ::: "memory");   // va(t) ready
        __builtin_amdgcn_s_barrier();                      // compute(t-1) done
        __builtin_amdgcn_sched_barrier(0);
        writeA(vaCur);
        if (t + 1 < KT) {
            loadA(t + 1, vaNxt);
            stageB(nxtbuf, t + 1);
            // outstanding: B(t)=4 oldest, va(t+1)=4, B(t+1)=4
            asm volatile("s_waitcnt vmcnt(8)" ::: "memory");  // B(t) landed
        } else {
            asm volatile("s_waitcnt vmcnt(0)" ::: "memory");
        }
        asm volatile("s_waitcnt lgkmcnt(0)" ::: "memory");    // A writes done
        __builtin_amdgcn_s_barrier();
        __builtin_amdgcn_sched_barrier(0);
        compute(curbuf);
    };

    // ---- prologue: A(0) regs + B(0) DMA in flight ----
    float4 vaA[4], vaB[4];
    loadA(0, vaA);
    stageB(0, 0);

#pragma unroll
    for (int tp = 0; tp < KT / 2; ++tp) {
        step(2 * tp,     vaA, vaB, 0, 1);
        step(2 * tp + 1, vaB, vaA, 1, 0);
    }

    // ---- epilogue: +0.5x identity (L2-hot), relu, interleaved float2 store ----
#pragma unroll
    for (int mi = 0; mi < 2; ++mi) {
#pragma unroll
        for (int nj = 0; nj < 4; ++nj) {
            int colp = bnp + wc * 64 + nj * 16 + l15;
            if (colp < PP) {
#pragma unroll
                for (int rr = 0; rr < 4; ++rr) {
                    int rowg = bm + wr * 32 + mi * 16 + lhi * 4 + rr;
                    size_t base = (size_t)rowg * CC + 2 * colp;
                    float2 xv = *(const float2*)&x[base];
                    float2 o;
                    float ye = 0.5f * xv.x + acc_e[mi][nj][rr];
                    float yo = 0.5f * xv.y + acc_o[mi][nj][rr];
                    o.x = ye > 0.f ? ye : 0.f;
                    o.y = yo > 0.f ? yo : 0.f;
                    *(float2*)&out[base] = o;
                }
            }
        }
    }
}

extern "C" void kernel_launch(void* const* d_in, const int* in_sizes, int n_in,
                              void* d_out, int out_size, void* d_ws, size_t ws_size,
                              hipStream_t stream) {
    const float* x = (const float*)d_in[0];
    float* out = (float*)d_out;

    unsigned short* bt1 = (unsigned short*)d_ws;            // 384*384 bf16
    unsigned short* bt2 = bt1 + KP * KP;                    // 384*384 bf16

    build_bt<<<(2 * KP * KP + 255) / 256, 256, 0, stream>>>(bt1, bt2);
    gemm_relu<<<NWG, 256, 0, stream>>>(x, bt1, bt2, out);
}